// Round 9
// baseline (58.718 us; speedup 1.0000x reference)
//
#include <hip/hip_runtime.h>
#include <math.h>

#define BDIM 512
#define DDIM 512

constexpr float EPS   = 1e-6f;
constexpr float HEPS  = 0.5e-6f;
constexpr float LN2   = 0.6931471805599453f;
constexpr float LOG2E = 1.4426950408889634f;

__device__ __forceinline__ float wave_reduce_sum(float v) {
  #pragma unroll
  for (int o = 32; o > 0; o >>= 1) v += __shfl_down(v, o, 64);
  return v;
}
__device__ __forceinline__ float wave_reduce_max(float v) {
  #pragma unroll
  for (int o = 32; o > 0; o >>= 1) v = fmaxf(v, __shfl_down(v, o, 64));
  return v;
}

// ---------------------------------------------------------------------------
// Kernel 1: per-row l2-normalize mu; emit SoA outputs:
// nX[r][d] = normalized mu, sX[r][d] = 0.5*sigma + 0.5*EPS  (sv = sA+sB).
// Also ld[r] = sum_d ln(sigma+EPS), mrow[r] = mean sigma.
// ---------------------------------------------------------------------------
__global__ __launch_bounds__(256) void prep_kernel(
    const float* __restrict__ mu1, const float* __restrict__ s1,
    const float* __restrict__ mu2, const float* __restrict__ s2,
    float* __restrict__ nA, float* __restrict__ sA,
    float* __restrict__ nB, float* __restrict__ sB,
    float* __restrict__ ld,         // ld1 at 0, ld2 at +B
    float* __restrict__ mrow) {     // m1 at 0, m2 at +B
  const int r = blockIdx.x;
  const int which = blockIdx.y;
  const float* __restrict__ mu = which ? mu2 : mu1;
  const float* __restrict__ sg = which ? s2 : s1;
  float* __restrict__ nout = which ? nB : nA;
  float* __restrict__ sout = which ? sB : sA;
  const int t = threadIdx.x;

  const float a  = mu[r * DDIM + t];
  const float b  = mu[r * DDIM + t + 256];
  const float sa = sg[r * DDIM + t];
  const float sb = sg[r * DDIM + t + 256];

  float v0 = a * a + b * b;
  float v1 = __log2f(sa + EPS) + __log2f(sb + EPS);
  float v2 = sa + sb;

  __shared__ float red[3][4];
  __shared__ float sinv;
  const int wid = t >> 6, lane = t & 63;
  v0 = wave_reduce_sum(v0);
  v1 = wave_reduce_sum(v1);
  v2 = wave_reduce_sum(v2);
  if (lane == 0) { red[0][wid] = v0; red[1][wid] = v1; red[2][wid] = v2; }
  __syncthreads();
  if (t == 0) {
    float sq = red[0][0] + red[0][1] + red[0][2] + red[0][3];
    float lg = red[1][0] + red[1][1] + red[1][2] + red[1][3];
    float sm = red[2][0] + red[2][1] + red[2][2] + red[2][3];
    ld[which * BDIM + r]   = LN2 * lg;
    mrow[which * BDIM + r] = sm * (1.0f / DDIM);
    sinv = 1.0f / fmaxf(sqrtf(sq), 1e-12f);
  }
  __syncthreads();
  const float inv = sinv;
  nout[r * DDIM + t]       = a * inv;
  nout[r * DDIM + t + 256] = b * inv;
  sout[r * DDIM + t]       = fmaf(0.5f, sa, HEPS);
  sout[r * DDIM + t + 256] = fmaf(0.5f, sb, HEPS);
}

// ---------------------------------------------------------------------------
// Kernel 2: B^2*D partial pass — 4x4 register blocking to beat the LDS pipe.
// Grid (8,8,8): one 256-thread block per (64x64 tile, 64-d slice) = 512
// blocks = exactly 2/CU (one pass). LDS: 4 SoA regions [64 rows][17 float4]
// (69632 B -> 2 blocks/CU -> VGPR cap 256; kernel needs ~140, no spill).
// Thread (ti,tj)=(t>>4,t&15) owns rows {16q+ti} x cols {16q+tj} — the
// 16-strided mapping makes B-reads walk 17*tj f4 across all 8 bank-groups
// (4-strided mapping would be 8-way conflicted). Per 4-d chunk: 16 b128
// reads -> 64 updates (0.25 instr/update, 4 B/update). Stage once, one
// sync, then barrier-free. log2 over products of 8 d. Direct per-thread
// scalar partial writes (no combine tail).
// ---------------------------------------------------------------------------
__global__ __launch_bounds__(256) void bd_kernel(
    const float* __restrict__ nA, const float* __restrict__ sA,
    const float* __restrict__ nB, const float* __restrict__ sB,
    float* __restrict__ t1p, float* __restrict__ ldap,
    float* __restrict__ dacp) {
  __shared__ __align__(16) float4 lds[4 * 64 * 17];   // 69632 B

  const int t  = threadIdx.x;
  const int i0 = blockIdx.y * 64, j0 = blockIdx.x * 64;
  const int z  = blockIdx.z;       // 0..7 (64-d slice)
  const int ti = t >> 4;           // 0..15
  const int tj = t & 15;           // 0..15

  // ---- stage: 4 arrays x 64 rows x 16 float4 = 4096 f4, 16 per thread ----
  {
    const float* __restrict__ srcs[4] = { nA, sA, nB, sB };
    #pragma unroll
    for (int it = 0; it < 16; ++it) {
      const int arr = it >> 2;            // compile-time per unrolled it
      const int rem = (it & 3) * 256 + t; // 0..1023
      const int row = rem >> 4;           // 0..63
      const int dc  = rem & 15;           // f4 within slice
      const int grow = (arr < 2 ? i0 : j0) + row;
      lds[arr * 1088 + row * 17 + dc] =
          *(const float4*)&srcs[arr][grow * DDIM + z * 64 + dc * 4];
    }
  }
  __syncthreads();

  // ---- barrier-free main loop: 16 chunks of 4 d ----
  float t1[4][4]  = {};
  float lda[4][4] = {};
  float dac[4][4] = {};

  const float4* __restrict__ pAn = lds + 0 * 1088 + ti * 17;
  const float4* __restrict__ pAs = lds + 1 * 1088 + ti * 17;
  const float4* __restrict__ pBn = lds + 2 * 1088 + tj * 17;
  const float4* __restrict__ pBs = lds + 3 * 1088 + tj * 17;

  for (int g2 = 0; g2 < 8; ++g2) {       // 8 x (2 chunks) = 8 d per m-batch
    float m[4][4] = {{1.f,1.f,1.f,1.f},{1.f,1.f,1.f,1.f},
                     {1.f,1.f,1.f,1.f},{1.f,1.f,1.f,1.f}};
    #pragma unroll
    for (int h = 0; h < 2; ++h) {
      const int dc = g2 * 2 + h;
      float4 An[4], As[4], Bn[4], Bs[4];
      #pragma unroll
      for (int q = 0; q < 4; ++q) {
        An[q] = pAn[q * 272 + dc];       // 272 = 16 rows * 17 f4
        As[q] = pAs[q * 272 + dc];
        Bn[q] = pBn[q * 272 + dc];
        Bs[q] = pBs[q * 272 + dc];
      }
      #pragma unroll
      for (int dd = 0; dd < 4; ++dd) {
        #pragma unroll
        for (int qi = 0; qi < 4; ++qi) {
          const float an = ((const float*)&An[qi])[dd];
          const float as = ((const float*)&As[qi])[dd];
          #pragma unroll
          for (int qj = 0; qj < 4; ++qj) {
            const float bn = ((const float*)&Bn[qj])[dd];
            const float bs = ((const float*)&Bs[qj])[dd];
            const float sv = as + bs;
            const float df = an - bn;
            t1[qi][qj]  = fmaf(df * df, __builtin_amdgcn_rcpf(sv), t1[qi][qj]);
            m[qi][qj]  *= sv;
            dac[qi][qj] = fmaf(an, bn, dac[qi][qj]);
          }
        }
      }
    }
    #pragma unroll
    for (int qi = 0; qi < 4; ++qi)
      #pragma unroll
      for (int qj = 0; qj < 4; ++qj)
        lda[qi][qj] += __log2f(m[qi][qj]);
  }

  // ---- direct per-thread partial writes (plane z) ----
  const size_t zb = (size_t)z * BDIM * BDIM;
  #pragma unroll
  for (int qi = 0; qi < 4; ++qi) {
    #pragma unroll
    for (int qj = 0; qj < 4; ++qj) {
      const size_t o = zb + (size_t)(i0 + 16 * qi + ti) * BDIM
                          + j0 + 16 * qj + tj;
      t1p[o]  = t1[qi][qj];
      ldap[o] = lda[qi][qj];
      dacp[o] = dac[qi][qj];
    }
  }
}

// ---------------------------------------------------------------------------
// Kernel 3: combine z-partials -> sim, pdiag, per-row off-diag max, AND the
// fused row-LSE of logits = scale*sim plus dlog (block i holds full row i).
// ---------------------------------------------------------------------------
__global__ __launch_bounds__(256) void combine_kernel(
    const float* __restrict__ t1p, const float* __restrict__ ldap,
    const float* __restrict__ dacp, const float* __restrict__ ld,
    const float* __restrict__ lscale,
    float* __restrict__ sim, float* __restrict__ pmaxf,
    float* __restrict__ pdiag, float* __restrict__ lse_row,
    float* __restrict__ dlog) {
  const int i = blockIdx.x;
  const int t = threadIdx.x;
  const float l1 = ld[i];
  const float sc = *lscale;
  float rmax = 0.f;
  float lg[2];
  #pragma unroll
  for (int q = 0; q < 2; ++q) {
    const int j = t + q * 256;
    const size_t o = (size_t)i * BDIM + j;
    float t1 = 0.f, lda = 0.f, dac = 0.f;
    #pragma unroll
    for (int zz = 0; zz < 8; ++zz) {
      const size_t idx = (size_t)zz * BDIM * BDIM + o;
      t1 += t1p[idx]; lda += ldap[idx]; dac += dacp[idx];
    }
    const float bd = fmaf(0.125f, t1,
                          0.5f * (LN2 * lda - 0.5f * (l1 + ld[BDIM + j])));
    const float sv = exp2f(bd * (-LOG2E / (float)DDIM));
    sim[o] = sv;
    lg[q] = sc * sv;
    const float p = exp2f((2.0f * LOG2E) * dac);
    if (j == i) { pdiag[i] = p; dlog[i] = sc * sv; }
    else        rmax = fmaxf(rmax, p);
  }
  __shared__ float red[4];
  const int wid = t >> 6, lane = t & 63;

  // off-diag p row max
  float wm = wave_reduce_max(rmax);
  if (lane == 0) red[wid] = wm;
  __syncthreads();
  if (t == 0) pmaxf[i] = fmaxf(fmaxf(red[0], red[1]), fmaxf(red[2], red[3]));
  __syncthreads();

  // row LSE of logits
  float rm = wave_reduce_max(fmaxf(lg[0], lg[1]));
  if (lane == 0) red[wid] = rm;
  __syncthreads();
  rm = fmaxf(fmaxf(red[0], red[1]), fmaxf(red[2], red[3]));
  __syncthreads();
  float rs = wave_reduce_sum(exp2f((lg[0] - rm) * LOG2E) +
                             exp2f((lg[1] - rm) * LOG2E));
  if (lane == 0) red[wid] = rs;
  __syncthreads();
  if (t == 0)
    lse_row[i] = rm + LN2 * __log2f(red[0] + red[1] + red[2] + red[3]);
}

// ---------------------------------------------------------------------------
// Kernel 4: per-column LSE of logits = scale*sim (rows done in combine).
// ---------------------------------------------------------------------------
__global__ __launch_bounds__(256) void lse_col_kernel(
    const float* __restrict__ sim, const float* __restrict__ lscale,
    float* __restrict__ lse_col) {
  const int b = blockIdx.x;
  const int t = threadIdx.x;
  const float sc = *lscale;
  const float c0 = sc * sim[t * BDIM + b];
  const float c1 = sc * sim[(t + 256) * BDIM + b];

  __shared__ float red[4];
  const int wid = t >> 6, lane = t & 63;

  float cm = wave_reduce_max(fmaxf(c0, c1));
  if (lane == 0) red[wid] = cm;
  __syncthreads();
  cm = fmaxf(fmaxf(red[0], red[1]), fmaxf(red[2], red[3]));
  __syncthreads();

  float cs = wave_reduce_sum(exp2f((c0 - cm) * LOG2E) + exp2f((c1 - cm) * LOG2E));
  if (lane == 0) red[wid] = cs;
  __syncthreads();
  if (t == 0)
    lse_col[b] = cm + LN2 * __log2f(red[0] + red[1] + red[2] + red[3]);
}

// ---------------------------------------------------------------------------
// Kernel 5: final reductions -> 3 scalars.
// ---------------------------------------------------------------------------
__global__ __launch_bounds__(512) void final_kernel(
    const float* __restrict__ pdiag, const float* __restrict__ pmaxf,
    const float* __restrict__ mrow, const float* __restrict__ lse_row,
    const float* __restrict__ lse_col, const float* __restrict__ dlog,
    float* __restrict__ out) {
  const int t = threadIdx.x;  // 0..511
  const float pm = pmaxf[t];
  const float u  = exp2f(-(pdiag[t] / pm) * LOG2E);   // exp(-diag/negmax)
  const float as = 0.5f * (mrow[t] + mrow[BDIM + t]);

  float vals[6];
  vals[0] = u;
  vals[1] = u * u;
  vals[2] = as * as;
  vals[3] = u * as;
  vals[4] = lse_row[t] - dlog[t];
  vals[5] = lse_col[t] - dlog[t];

  __shared__ float red[6][8];
  const int wid = t >> 6, lane = t & 63;
  #pragma unroll
  for (int k = 0; k < 6; ++k) {
    const float v = wave_reduce_sum(vals[k]);
    if (lane == 0) red[k][wid] = v;
  }
  __syncthreads();
  if (t == 0) {
    float s[6];
    #pragma unroll
    for (int k = 0; k < 6; ++k) {
      float a = 0.f;
      #pragma unroll
      for (int w = 0; w < 8; ++w) a += red[k][w];
      s[k] = a;
    }
    const float mean_u = s[0] * (1.0f / BDIM);
    const float cosv = s[3] / fmaxf(sqrtf(s[1]) * sqrtf(s[2]), 1e-24f);
    out[0] = 0.5f * (s[4] + s[5]) * (1.0f / BDIM);  // loss_pro
    out[1] = 2.4f * (1.0f - cosv);                  // loss_rank * 2.4
    out[2] = 0.5f * mean_u;                         // var_loss
  }
}

extern "C" void kernel_launch(void* const* d_in, const int* in_sizes, int n_in,
                              void* d_out, int out_size, void* d_ws, size_t ws_size,
                              hipStream_t stream) {
  const float* mu1 = (const float*)d_in[0];
  const float* s1  = (const float*)d_in[1];
  const float* mu2 = (const float*)d_in[2];
  const float* s2  = (const float*)d_in[3];
  const float* lsc = (const float*)d_in[4];
  float* out = (float*)d_out;

  float* ws      = (float*)d_ws;
  float* nA      = ws;                                // 1MB each
  float* sA      = nA + BDIM * DDIM;
  float* nB      = sA + BDIM * DDIM;
  float* sB      = nB + BDIM * DDIM;
  float* sim     = sB + BDIM * DDIM;                  // 1MB
  float* t1p     = sim + BDIM * BDIM;                 // 8 * 1MB
  float* ldap    = t1p + 8 * BDIM * BDIM;             // 8 * 1MB
  float* dacp    = ldap + 8 * BDIM * BDIM;            // 8 * 1MB
  float* ld      = dacp + 8 * BDIM * BDIM;            // 2*512
  float* mrow    = ld + 2 * BDIM;                     // 2*512
  float* pmaxf   = mrow + 2 * BDIM;                   // 512
  float* pdiag   = pmaxf + BDIM;                      // 512
  float* lse_row = pdiag + BDIM;                      // 512
  float* lse_col = lse_row + BDIM;                    // 512
  float* dlog    = lse_col + BDIM;                    // 512

  prep_kernel<<<dim3(BDIM, 2), 256, 0, stream>>>(mu1, s1, mu2, s2, nA, sA,
                                                 nB, sB, ld, mrow);
  bd_kernel<<<dim3(8, 8, 8), 256, 0, stream>>>(nA, sA, nB, sB, t1p, ldap,
                                               dacp);
  combine_kernel<<<BDIM, 256, 0, stream>>>(t1p, ldap, dacp, ld, lsc, sim,
                                           pmaxf, pdiag, lse_row, dlog);
  lse_col_kernel<<<BDIM, 256, 0, stream>>>(sim, lsc, lse_col);
  final_kernel<<<1, 512, 0, stream>>>(pdiag, pmaxf, mrow, lse_row, lse_col,
                                      dlog, out);
}

// Round 11
// 53.909 us; speedup vs baseline: 1.0892x; 1.0892x over previous
//
#include <hip/hip_runtime.h>
#include <math.h>

#define BDIM 512
#define DDIM 512

constexpr float EPS   = 1e-6f;
constexpr float HEPS  = 0.5e-6f;
constexpr float LN2   = 0.6931471805599453f;
constexpr float LOG2E = 1.4426950408889634f;

__device__ __forceinline__ float wave_reduce_sum(float v) {
  #pragma unroll
  for (int o = 32; o > 0; o >>= 1) v += __shfl_down(v, o, 64);
  return v;
}
__device__ __forceinline__ float wave_reduce_max(float v) {
  #pragma unroll
  for (int o = 32; o > 0; o >>= 1) v = fmaxf(v, __shfl_down(v, o, 64));
  return v;
}

// ---------------------------------------------------------------------------
// Kernel 1: per-row l2-normalize mu; SoA outputs nA/sA/nB/sB
// (sX = 0.5*sigma + 0.5*EPS so sv = sA+sB), ld, mrow.
// ---------------------------------------------------------------------------
__global__ __launch_bounds__(256) void prep_kernel(
    const float* __restrict__ mu1, const float* __restrict__ s1,
    const float* __restrict__ mu2, const float* __restrict__ s2,
    float* __restrict__ nA, float* __restrict__ sA,
    float* __restrict__ nB, float* __restrict__ sB,
    float* __restrict__ ld,         // ld1 at 0, ld2 at +B
    float* __restrict__ mrow) {     // m1 at 0, m2 at +B
  const int r = blockIdx.x;
  const int which = blockIdx.y;
  const float* __restrict__ mu = which ? mu2 : mu1;
  const float* __restrict__ sg = which ? s2 : s1;
  float* __restrict__ nout = which ? nB : nA;
  float* __restrict__ sout = which ? sB : sA;
  const int t = threadIdx.x;

  const float a  = mu[r * DDIM + t];
  const float b  = mu[r * DDIM + t + 256];
  const float sa = sg[r * DDIM + t];
  const float sb = sg[r * DDIM + t + 256];

  float v0 = a * a + b * b;
  float v1 = __log2f(sa + EPS) + __log2f(sb + EPS);
  float v2 = sa + sb;

  __shared__ float red[3][4];
  __shared__ float sinv;
  const int wid = t >> 6, lane = t & 63;
  v0 = wave_reduce_sum(v0);
  v1 = wave_reduce_sum(v1);
  v2 = wave_reduce_sum(v2);
  if (lane == 0) { red[0][wid] = v0; red[1][wid] = v1; red[2][wid] = v2; }
  __syncthreads();
  if (t == 0) {
    float sq = red[0][0] + red[0][1] + red[0][2] + red[0][3];
    float lg = red[1][0] + red[1][1] + red[1][2] + red[1][3];
    float sm = red[2][0] + red[2][1] + red[2][2] + red[2][3];
    ld[which * BDIM + r]   = LN2 * lg;
    mrow[which * BDIM + r] = sm * (1.0f / DDIM);
    sinv = 1.0f / fmaxf(sqrtf(sq), 1e-12f);
  }
  __syncthreads();
  const float inv = sinv;
  nout[r * DDIM + t]       = a * inv;
  nout[r * DDIM + t + 256] = b * inv;
  sout[r * DDIM + t]       = fmaf(0.5f, sa, HEPS);
  sout[r * DDIM + t + 256] = fmaf(0.5f, sb, HEPS);
}

// ---------------------------------------------------------------------------
// Kernel 2: B^2*D partial pass — 4x4 blocking + PAIRED-RCP inner loop.
// Grid (8,8,8), 256 threads, 64x64 tile, 64-d slice, LDS 69632B (2/CU).
// Per d-pair per cell: df0^2/sv0 + df1^2/sv1 = (df0^2*sv1 + df1^2*sv0)
// * rcp(sv0*sv1), and m *= (sv0*sv1) reuses the product -> rcp count
// halves (134M -> 67M), 13 VALU / pair. log2 over products of 8 sv
// (4 pairs) exactly as before (no new underflow exposure).
// ---------------------------------------------------------------------------
__global__ __launch_bounds__(256) void bd_kernel(
    const float* __restrict__ nA, const float* __restrict__ sA,
    const float* __restrict__ nB, const float* __restrict__ sB,
    float* __restrict__ t1p, float* __restrict__ ldap,
    float* __restrict__ dacp) {
  __shared__ __align__(16) float4 lds[4 * 64 * 17];   // 69632 B

  const int t  = threadIdx.x;
  const int i0 = blockIdx.y * 64, j0 = blockIdx.x * 64;
  const int z  = blockIdx.z;       // 0..7 (64-d slice)
  const int ti = t >> 4;           // 0..15
  const int tj = t & 15;           // 0..15

  // stage: 4 arrays x 64 rows x 16 float4; explicit per-array loops.
  #pragma unroll
  for (int q = 0; q < 4; ++q) {
    const int rem = q * 256 + t, row = rem >> 4, dc = rem & 15;
    lds[0 * 1088 + row * 17 + dc] =
        *(const float4*)&nA[(i0 + row) * DDIM + z * 64 + dc * 4];
  }
  #pragma unroll
  for (int q = 0; q < 4; ++q) {
    const int rem = q * 256 + t, row = rem >> 4, dc = rem & 15;
    lds[1 * 1088 + row * 17 + dc] =
        *(const float4*)&sA[(i0 + row) * DDIM + z * 64 + dc * 4];
  }
  #pragma unroll
  for (int q = 0; q < 4; ++q) {
    const int rem = q * 256 + t, row = rem >> 4, dc = rem & 15;
    lds[2 * 1088 + row * 17 + dc] =
        *(const float4*)&nB[(j0 + row) * DDIM + z * 64 + dc * 4];
  }
  #pragma unroll
  for (int q = 0; q < 4; ++q) {
    const int rem = q * 256 + t, row = rem >> 4, dc = rem & 15;
    lds[3 * 1088 + row * 17 + dc] =
        *(const float4*)&sB[(j0 + row) * DDIM + z * 64 + dc * 4];
  }
  __syncthreads();

  float t1[4][4]  = {};
  float lda[4][4] = {};
  float dac[4][4] = {};

  const float4* __restrict__ pAn = lds + 0 * 1088 + ti * 17;
  const float4* __restrict__ pAs = lds + 1 * 1088 + ti * 17;
  const float4* __restrict__ pBn = lds + 2 * 1088 + tj * 17;
  const float4* __restrict__ pBs = lds + 3 * 1088 + tj * 17;

  for (int g2 = 0; g2 < 8; ++g2) {       // 8 x (2 f4) = 8 d per m-batch
    float m[4][4] = {{1.f,1.f,1.f,1.f},{1.f,1.f,1.f,1.f},
                     {1.f,1.f,1.f,1.f},{1.f,1.f,1.f,1.f}};
    #pragma unroll
    for (int h = 0; h < 2; ++h) {
      const int dc = g2 * 2 + h;
      float4 Bn[4], Bs[4];
      #pragma unroll
      for (int q = 0; q < 4; ++q) Bn[q] = pBn[q * 272 + dc];
      #pragma unroll
      for (int q = 0; q < 4; ++q) Bs[q] = pBs[q * 272 + dc];
      #pragma unroll
      for (int qi = 0; qi < 4; ++qi) {
        const float4 An = pAn[qi * 272 + dc];
        const float4 As = pAs[qi * 272 + dc];
        #pragma unroll
        for (int p2 = 0; p2 < 2; ++p2) {   // d-pairs (0,1) and (2,3)
          const float an0 = ((const float*)&An)[2 * p2];
          const float an1 = ((const float*)&An)[2 * p2 + 1];
          const float as0 = ((const float*)&As)[2 * p2];
          const float as1 = ((const float*)&As)[2 * p2 + 1];
          #pragma unroll
          for (int qj = 0; qj < 4; ++qj) {
            const float bn0 = ((const float*)&Bn[qj])[2 * p2];
            const float bn1 = ((const float*)&Bn[qj])[2 * p2 + 1];
            const float bs0 = ((const float*)&Bs[qj])[2 * p2];
            const float bs1 = ((const float*)&Bs[qj])[2 * p2 + 1];
            const float sv0 = as0 + bs0;
            const float sv1 = as1 + bs1;
            const float svp = sv0 * sv1;
            const float df0 = an0 - bn0;
            const float df1 = an1 - bn1;
            float num = (df0 * df0) * sv1;
            num = fmaf(df1 * df1, sv0, num);
            t1[qi][qj]  = fmaf(num, __builtin_amdgcn_rcpf(svp), t1[qi][qj]);
            m[qi][qj]  *= svp;
            dac[qi][qj] = fmaf(an0, bn0, dac[qi][qj]);
            dac[qi][qj] = fmaf(an1, bn1, dac[qi][qj]);
          }
        }
      }
    }
    #pragma unroll
    for (int qi = 0; qi < 4; ++qi)
      #pragma unroll
      for (int qj = 0; qj < 4; ++qj)
        lda[qi][qj] += __log2f(m[qi][qj]);
  }

  const size_t zb = (size_t)z * BDIM * BDIM;
  #pragma unroll
  for (int qi = 0; qi < 4; ++qi) {
    #pragma unroll
    for (int qj = 0; qj < 4; ++qj) {
      const size_t o = zb + (size_t)(i0 + 16 * qi + ti) * BDIM
                          + j0 + 16 * qj + tj;
      t1p[o]  = t1[qi][qj];
      ldap[o] = lda[qi][qj];
      dacp[o] = dac[qi][qj];
    }
  }
}

// ---------------------------------------------------------------------------
// Kernel 3: combine z-partials -> sim, pdiag, per-row off-diag max, fused
// row-LSE + dlog.
// ---------------------------------------------------------------------------
__global__ __launch_bounds__(256) void combine_kernel(
    const float* __restrict__ t1p, const float* __restrict__ ldap,
    const float* __restrict__ dacp, const float* __restrict__ ld,
    const float* __restrict__ lscale,
    float* __restrict__ sim, float* __restrict__ pmaxf,
    float* __restrict__ pdiag, float* __restrict__ lse_row,
    float* __restrict__ dlog) {
  const int i = blockIdx.x;
  const int t = threadIdx.x;
  const float l1 = ld[i];
  const float sc = *lscale;
  float rmax = 0.f;
  float lg[2];
  #pragma unroll
  for (int q = 0; q < 2; ++q) {
    const int j = t + q * 256;
    const size_t o = (size_t)i * BDIM + j;
    float t1 = 0.f, lda = 0.f, dac = 0.f;
    #pragma unroll
    for (int zz = 0; zz < 8; ++zz) {
      const size_t idx = (size_t)zz * BDIM * BDIM + o;
      t1 += t1p[idx]; lda += ldap[idx]; dac += dacp[idx];
    }
    const float bd = fmaf(0.125f, t1,
                          0.5f * (LN2 * lda - 0.5f * (l1 + ld[BDIM + j])));
    const float sv = exp2f(bd * (-LOG2E / (float)DDIM));
    sim[o] = sv;
    lg[q] = sc * sv;
    const float p = exp2f((2.0f * LOG2E) * dac);
    if (j == i) { pdiag[i] = p; dlog[i] = sc * sv; }
    else        rmax = fmaxf(rmax, p);
  }
  __shared__ float red[4];
  const int wid = t >> 6, lane = t & 63;

  float wm = wave_reduce_max(rmax);
  if (lane == 0) red[wid] = wm;
  __syncthreads();
  if (t == 0) pmaxf[i] = fmaxf(fmaxf(red[0], red[1]), fmaxf(red[2], red[3]));
  __syncthreads();

  float rm = wave_reduce_max(fmaxf(lg[0], lg[1]));
  if (lane == 0) red[wid] = rm;
  __syncthreads();
  rm = fmaxf(fmaxf(red[0], red[1]), fmaxf(red[2], red[3]));
  __syncthreads();
  float rs = wave_reduce_sum(exp2f((lg[0] - rm) * LOG2E) +
                             exp2f((lg[1] - rm) * LOG2E));
  if (lane == 0) red[wid] = rs;
  __syncthreads();
  if (t == 0)
    lse_row[i] = rm + LN2 * __log2f(red[0] + red[1] + red[2] + red[3]);
}

// ---------------------------------------------------------------------------
// Kernel 4: per-column LSE of logits = scale*sim.
// ---------------------------------------------------------------------------
__global__ __launch_bounds__(256) void lse_col_kernel(
    const float* __restrict__ sim, const float* __restrict__ lscale,
    float* __restrict__ lse_col) {
  const int b = blockIdx.x;
  const int t = threadIdx.x;
  const float sc = *lscale;
  const float c0 = sc * sim[t * BDIM + b];
  const float c1 = sc * sim[(t + 256) * BDIM + b];

  __shared__ float red[4];
  const int wid = t >> 6, lane = t & 63;

  float cm = wave_reduce_max(fmaxf(c0, c1));
  if (lane == 0) red[wid] = cm;
  __syncthreads();
  cm = fmaxf(fmaxf(red[0], red[1]), fmaxf(red[2], red[3]));
  __syncthreads();

  float cs = wave_reduce_sum(exp2f((c0 - cm) * LOG2E) + exp2f((c1 - cm) * LOG2E));
  if (lane == 0) red[wid] = cs;
  __syncthreads();
  if (t == 0)
    lse_col[b] = cm + LN2 * __log2f(red[0] + red[1] + red[2] + red[3]);
}

// ---------------------------------------------------------------------------
// Kernel 5: final reductions -> 3 scalars.
// ---------------------------------------------------------------------------
__global__ __launch_bounds__(512) void final_kernel(
    const float* __restrict__ pdiag, const float* __restrict__ pmaxf,
    const float* __restrict__ mrow, const float* __restrict__ lse_row,
    const float* __restrict__ lse_col, const float* __restrict__ dlog,
    float* __restrict__ out) {
  const int t = threadIdx.x;  // 0..511
  const float pm = pmaxf[t];
  const float u  = exp2f(-(pdiag[t] / pm) * LOG2E);   // exp(-diag/negmax)
  const float as = 0.5f * (mrow[t] + mrow[BDIM + t]);

  float vals[6];
  vals[0] = u;
  vals[1] = u * u;
  vals[2] = as * as;
  vals[3] = u * as;
  vals[4] = lse_row[t] - dlog[t];
  vals[5] = lse_col[t] - dlog[t];

  __shared__ float red[6][8];
  const int wid = t >> 6, lane = t & 63;
  #pragma unroll
  for (int k = 0; k < 6; ++k) {
    const float v = wave_reduce_sum(vals[k]);
    if (lane == 0) red[k][wid] = v;
  }
  __syncthreads();
  if (t == 0) {
    float s[6];
    #pragma unroll
    for (int k = 0; k < 6; ++k) {
      float a = 0.f;
      #pragma unroll
      for (int w = 0; w < 8; ++w) a += red[k][w];
      s[k] = a;
    }
    const float mean_u = s[0] * (1.0f / BDIM);
    const float cosv = s[3] / fmaxf(sqrtf(s[1]) * sqrtf(s[2]), 1e-24f);
    out[0] = 0.5f * (s[4] + s[5]) * (1.0f / BDIM);  // loss_pro
    out[1] = 2.4f * (1.0f - cosv);                  // loss_rank * 2.4
    out[2] = 0.5f * mean_u;                         // var_loss
  }
}

extern "C" void kernel_launch(void* const* d_in, const int* in_sizes, int n_in,
                              void* d_out, int out_size, void* d_ws, size_t ws_size,
                              hipStream_t stream) {
  const float* mu1 = (const float*)d_in[0];
  const float* s1  = (const float*)d_in[1];
  const float* mu2 = (const float*)d_in[2];
  const float* s2  = (const float*)d_in[3];
  const float* lsc = (const float*)d_in[4];
  float* out = (float*)d_out;

  float* ws      = (float*)d_ws;
  float* nA      = ws;                                // 1MB each
  float* sA      = nA + BDIM * DDIM;
  float* nB      = sA + BDIM * DDIM;
  float* sB      = nB + BDIM * DDIM;
  float* sim     = sB + BDIM * DDIM;                  // 1MB
  float* t1p     = sim + BDIM * BDIM;                 // 8 * 1MB
  float* ldap    = t1p + 8 * BDIM * BDIM;             // 8 * 1MB
  float* dacp    = ldap + 8 * BDIM * BDIM;            // 8 * 1MB
  float* ld      = dacp + 8 * BDIM * BDIM;            // 2*512
  float* mrow    = ld + 2 * BDIM;                     // 2*512
  float* pmaxf   = mrow + 2 * BDIM;                   // 512
  float* pdiag   = pmaxf + BDIM;                      // 512
  float* lse_row = pdiag + BDIM;                      // 512
  float* lse_col = lse_row + BDIM;                    // 512
  float* dlog    = lse_col + BDIM;                    // 512

  prep_kernel<<<dim3(BDIM, 2), 256, 0, stream>>>(mu1, s1, mu2, s2, nA, sA,
                                                 nB, sB, ld, mrow);
  bd_kernel<<<dim3(8, 8, 8), 256, 0, stream>>>(nA, sA, nB, sB, t1p, ldap,
                                               dacp);
  combine_kernel<<<BDIM, 256, 0, stream>>>(t1p, ldap, dacp, ld, lsc, sim,
                                           pmaxf, pdiag, lse_row, dlog);
  lse_col_kernel<<<BDIM, 256, 0, stream>>>(sim, lsc, lse_col);
  final_kernel<<<1, 512, 0, stream>>>(pdiag, pmaxf, mrow, lse_row, lse_col,
                                      dlog, out);
}